// Round 3
// baseline (1158.621 us; speedup 1.0000x reference)
//
#include <hip/hip_runtime.h>
#include <hip/hip_bf16.h>

#define R_ 1152
#define B_ 128
#define I_ 64
#define C_ 16
#define O_ 64
#define CO_ 1024  // C_*O_

typedef float f32x16 __attribute__((ext_vector_type(16)));

// ---------------- kernel 1: u_hat[b][r][c][o] = sum_i W[r][c][o][i] * x[b][i][r] ----
// grid = 1152 (one r per block), block = 512.
// x column staged to LDS transposed [i][b] (pad 4) -> compute reads are b128 broadcasts.
// thread t owns columns co = 2t, 2t+1 (W in 128 VGPRs), accumulates 4 b at a time.
__global__ __launch_bounds__(512, 1) void uhat_kernel(const float* __restrict__ x,
                                                      const float* __restrict__ W,
                                                      float* __restrict__ u) {
  const int r = blockIdx.x;
  const int t = threadIdx.x;
  __shared__ float xl[I_][B_ + 4];

  // prefetch W: 128 consecutive floats = cols 2t (first 64) and 2t+1 (next 64)
  const float4* wp = (const float4*)(W + ((size_t)r * CO_ + 2 * t) * I_);
  float4 wa[16], wb[16];
#pragma unroll
  for (int q = 0; q < 16; ++q) wa[q] = wp[q];
#pragma unroll
  for (int q = 0; q < 16; ++q) wb[q] = wp[16 + q];

  // stage x[(b*64+i)*1152 + r] -> xl[i][b]
#pragma unroll
  for (int k = 0; k < 16; ++k) {
    int bi = t + k * 512;
    xl[bi & 63][bi >> 6] = x[(size_t)bi * R_ + r];
  }
  __syncthreads();

  const size_t bstride = (size_t)R_ * CO_;
  const size_t obase = (size_t)r * CO_ + 2 * t;
#pragma unroll 1
  for (int b0 = 0; b0 < B_; b0 += 4) {
    float2 acc[4];
#pragma unroll
    for (int j = 0; j < 4; ++j) { acc[j].x = 0.f; acc[j].y = 0.f; }
#pragma unroll
    for (int q = 0; q < 16; ++q) {
      float4 xv0 = *(const float4*)&xl[4 * q + 0][b0];
      float4 xv1 = *(const float4*)&xl[4 * q + 1][b0];
      float4 xv2 = *(const float4*)&xl[4 * q + 2][b0];
      float4 xv3 = *(const float4*)&xl[4 * q + 3][b0];
#define STEP(xv, wc0, wc1)                                   \
      acc[0].x += xv.x * (wc0); acc[0].y += xv.x * (wc1);    \
      acc[1].x += xv.y * (wc0); acc[1].y += xv.y * (wc1);    \
      acc[2].x += xv.z * (wc0); acc[2].y += xv.z * (wc1);    \
      acc[3].x += xv.w * (wc0); acc[3].y += xv.w * (wc1);
      STEP(xv0, wa[q].x, wb[q].x)
      STEP(xv1, wa[q].y, wb[q].y)
      STEP(xv2, wa[q].z, wb[q].z)
      STEP(xv3, wa[q].w, wb[q].w)
#undef STEP
    }
#pragma unroll
    for (int j = 0; j < 4; ++j) {
      *(float2*)&u[obase + (size_t)(b0 + j) * bstride] = acc[j];
    }
  }
}

// ---------------- routing iteration (fused a_ij -> b_ij -> softmax -> partial s) ----
// MODE 0: c = 1/16 (iteration 0, b_ij == 0), no v/bij access.
// MODE 1: a = u.v ; b_ij = a (write, no read) ; softmax(a)
// MODE 2: a = u.v ; bn = b_ij + a (no write needed)   ; softmax(bn)
// grid = 128*36 blocks (b, 32-r chunk), block = 256 (4 waves x 8 r's each).
// lane l owns co = 16l..16l+15 (capsule c = l>>2); s accumulated in registers.
template <int MODE>
__global__ __launch_bounds__(256) void route_kernel(const float* __restrict__ u,
                                                    const float* __restrict__ vprev,
                                                    float* __restrict__ bij,
                                                    float* __restrict__ s) {
  const int blk = blockIdx.x;
  const int b = blk / 36;
  const int rc = blk % 36;
  const int w = threadIdx.x >> 6;
  const int l = threadIdx.x & 63;

  f32x16 vv;
  if (MODE != 0) {
    vv = *(const f32x16*)(vprev + (size_t)b * CO_ + l * 16);
  }
  f32x16 sacc;
#pragma unroll
  for (int j = 0; j < 16; ++j) sacc[j] = 0.f;

  for (int k = 0; k < 8; ++k) {
    const int r = rc * 32 + w * 8 + k;
    const f32x16 uu = *(const f32x16*)(u + ((size_t)b * R_ + r) * CO_ + l * 16);
    float cval;
    if (MODE == 0) {
      cval = 1.0f / 16.0f;
    } else {
      float p = 0.f;
#pragma unroll
      for (int j = 0; j < 16; ++j) p += uu[j] * vv[j];
      // reduce over the quad (lanes 4c..4c+3 hold capsule c's 64 o-elements)
      p += __shfl_xor(p, 1);
      p += __shfl_xor(p, 2);
      float bn = p;
      const size_t bidx = ((size_t)b * R_ + r) * C_ + (l >> 2);
      if (MODE == 2) bn += bij[bidx];
      if (MODE == 1 && (l & 3) == 0) bij[bidx] = bn;
      // softmax over 16 capsules: every c replicated x4 across the wave
      float mx = bn;
#pragma unroll
      for (int d = 1; d < 64; d <<= 1) mx = fmaxf(mx, __shfl_xor(mx, d));
      float e = __expf(bn - mx);
      float tot = e;
#pragma unroll
      for (int d = 1; d < 64; d <<= 1) tot += __shfl_xor(tot, d);
      cval = 4.0f * e / tot;  // wave sum counts each capsule 4x
    }
#pragma unroll
    for (int j = 0; j < 16; ++j) sacc[j] += cval * uu[j];
  }

  // combine the 4 waves' partial s, one atomicAdd per co
  __shared__ float sp[4][16][64];
#pragma unroll
  for (int j = 0; j < 16; ++j) sp[w][j][l] = sacc[j];
  __syncthreads();
#pragma unroll
  for (int q = 0; q < 4; ++q) {
    const int co = threadIdx.x + q * 256;
    const int jj = co & 15, ll = co >> 4;
    float val = sp[0][jj][ll] + sp[1][jj][ll] + sp[2][jj][ll] + sp[3][jj][ll];
    atomicAdd(&s[(size_t)b * CO_ + co], val);
  }
}

// ---------------- squash (elementwise, per reference) ----------------
__global__ __launch_bounds__(256) void squash_kernel(const float* __restrict__ s,
                                                     float* __restrict__ v) {
  const int i = blockIdx.x * 256 + threadIdx.x;
  const float t = s[i];
  const float sq = t * t;
  v[i] = sq / (1.0f + sq) * t * rsqrtf(sq + 1e-8f);
}

extern "C" void kernel_launch(void* const* d_in, const int* in_sizes, int n_in,
                              void* d_out, int out_size, void* d_ws, size_t ws_size,
                              hipStream_t stream) {
  (void)in_sizes; (void)n_in; (void)out_size; (void)ws_size;
  const float* x = (const float*)d_in[0];
  const float* W = (const float*)d_in[1];
  float* out = (float*)d_out;

  char* ws = (char*)d_ws;
  float* u = (float*)ws;                                   // 603,979,776 B
  size_t off = (size_t)B_ * R_ * CO_ * sizeof(float);
  float* bij = (float*)(ws + off);                         // 9,437,184 B
  off += (size_t)B_ * R_ * C_ * sizeof(float);
  float* s = (float*)(ws + off);                           // 524,288 B
  off += (size_t)B_ * CO_ * sizeof(float);
  float* vbuf = (float*)(ws + off);                        // 524,288 B

  const size_t s_bytes = (size_t)B_ * CO_ * sizeof(float);

  uhat_kernel<<<R_, 512, 0, stream>>>(x, W, u);

  // iteration 0: c = 1/16
  hipMemsetAsync(s, 0, s_bytes, stream);
  route_kernel<0><<<B_ * 36, 256, 0, stream>>>(u, nullptr, bij, s);
  squash_kernel<<<(B_ * CO_) / 256, 256, 0, stream>>>(s, vbuf);

  // iteration 1: b = a1
  hipMemsetAsync(s, 0, s_bytes, stream);
  route_kernel<1><<<B_ * 36, 256, 0, stream>>>(u, vbuf, bij, s);
  squash_kernel<<<(B_ * CO_) / 256, 256, 0, stream>>>(s, vbuf);

  // iteration 2: b = a1 + a2
  hipMemsetAsync(s, 0, s_bytes, stream);
  route_kernel<2><<<B_ * 36, 256, 0, stream>>>(u, vbuf, bij, s);
  squash_kernel<<<(B_ * CO_) / 256, 256, 0, stream>>>(s, out);
}

// Round 5
// 1067.289 us; speedup vs baseline: 1.0856x; 1.0856x over previous
//
#include <hip/hip_runtime.h>
#include <hip/hip_bf16.h>

#define R_ 1152
#define B_ 128
#define I_ 64
#define C_ 16
#define O_ 64
#define CO_ 1024  // C_*O_

typedef float f32x16 __attribute__((ext_vector_type(16)));

// u is stored PERMUTED: u_perm[(b*R + r)*1024 + p] where p = j4*256 + l*4 + e
// and the logical column is co = l*16 + (j4*4 + e), l in [0,64), j4 in [0,4), e in [0,4).
// This makes route reads lane-contiguous (lane l reads float4 at p = j4*256 + l*4)
// and uhat stores linear in plin.

// ---------------- kernel 1: u_hat ----------------
// grid = 2304 (= 1152 r x 2 co-halves), block = 512, one W column per thread (64 VGPR).
__global__ __launch_bounds__(512) void uhat_kernel(const float* __restrict__ x,
                                                   const float* __restrict__ W,
                                                   float* __restrict__ u) {
  // XCD-chunked swizzle: 2304 blocks = 8 XCDs x 288, keeps contiguous r on one XCD
  // so the 16-r-wide x cache lines are reused within a single L2.
  const int id = blockIdx.x;
  const int swz = (id & 7) * 288 + (id >> 3);
  const int r = swz >> 1;
  const int h = swz & 1;
  const int t = threadIdx.x;

  __shared__ float xl[I_][B_ + 4];
  // stage x[b][i][r] -> xl[i][b]; b = t&127 across lanes => conflict-free LDS writes
#pragma unroll
  for (int p = 0; p < 16; ++p) {
    const int b = t & 127;
    const int i = (t >> 7) + p * 4;
    xl[i][b] = x[((size_t)(b * 64 + i)) * R_ + r];
  }

  // this thread's output slot and logical column
  const int plin = h * 512 + t;
  const int l = (plin >> 2) & 63;
  const int j4 = plin >> 8;
  const int e = plin & 3;
  const int co = l * 16 + j4 * 4 + e;

  float4 w[16];
  const float4* wp = (const float4*)(W + ((size_t)r * CO_ + co) * I_);
#pragma unroll
  for (int q = 0; q < 16; ++q) w[q] = wp[q];

  __syncthreads();

  float* uout = u + (size_t)r * CO_ + plin;
  const size_t bstride = (size_t)R_ * CO_;
#pragma unroll 1
  for (int b0 = 0; b0 < B_; b0 += 4) {
    float acc0 = 0.f, acc1 = 0.f, acc2 = 0.f, acc3 = 0.f;
#pragma unroll
    for (int q = 0; q < 16; ++q) {
      const float4 xv0 = *(const float4*)&xl[4 * q + 0][b0];
      const float4 xv1 = *(const float4*)&xl[4 * q + 1][b0];
      const float4 xv2 = *(const float4*)&xl[4 * q + 2][b0];
      const float4 xv3 = *(const float4*)&xl[4 * q + 3][b0];
      acc0 += w[q].x * xv0.x; acc0 += w[q].y * xv1.x; acc0 += w[q].z * xv2.x; acc0 += w[q].w * xv3.x;
      acc1 += w[q].x * xv0.y; acc1 += w[q].y * xv1.y; acc1 += w[q].z * xv2.y; acc1 += w[q].w * xv3.y;
      acc2 += w[q].x * xv0.z; acc2 += w[q].y * xv1.z; acc2 += w[q].z * xv2.z; acc2 += w[q].w * xv3.z;
      acc3 += w[q].x * xv0.w; acc3 += w[q].y * xv1.w; acc3 += w[q].z * xv2.w; acc3 += w[q].w * xv3.w;
    }
    uout[(size_t)(b0 + 0) * bstride] = acc0;
    uout[(size_t)(b0 + 1) * bstride] = acc1;
    uout[(size_t)(b0 + 2) * bstride] = acc2;
    uout[(size_t)(b0 + 3) * bstride] = acc3;
  }
}

// ---------------- routing iteration (fused a_ij -> b_ij -> softmax -> partial s) ----
// MODE 0: c = 1/16; MODE 1: b = a1 (write bij); MODE 2: b = bij + a2 (bij prefetched).
// grid = 128*36 (b, 32-r chunk), block = 256 (4 waves x 8 r).
// lane l owns co = l*16 .. l*16+15 (capsule c = l>>2); reads are lane-contiguous
// float4s from the permuted u layout.
template <int MODE>
__global__ __launch_bounds__(256) void route_kernel(const float* __restrict__ u,
                                                    const float* __restrict__ vprev,
                                                    float* __restrict__ bij,
                                                    float* __restrict__ s) {
  const int blk = blockIdx.x;
  const int b = blk / 36;
  const int rc = blk % 36;
  const int w = threadIdx.x >> 6;
  const int l = threadIdx.x & 63;
  const int rbase = rc * 32 + w * 8;

  f32x16 vv;
  if (MODE != 0) {
    vv = *(const f32x16*)(vprev + (size_t)b * CO_ + l * 16);
  }

  float bpre[8];
  if (MODE == 2) {
#pragma unroll
    for (int k = 0; k < 8; ++k)
      bpre[k] = bij[((size_t)b * R_ + rbase + k) * C_ + (l >> 2)];
  }

  float sacc[16];
#pragma unroll
  for (int j = 0; j < 16; ++j) sacc[j] = 0.f;

  const float* ub0 = u + ((size_t)b * R_ + rbase) * CO_ + l * 4;
#pragma unroll
  for (int k = 0; k < 8; ++k) {
    const float* ub = ub0 + (size_t)k * CO_;
    const float4 u0 = *(const float4*)(ub + 0);
    const float4 u1 = *(const float4*)(ub + 256);
    const float4 u2 = *(const float4*)(ub + 512);
    const float4 u3 = *(const float4*)(ub + 768);
    float cval;
    if (MODE == 0) {
      cval = 1.0f / 16.0f;
    } else {
      float p = 0.f;
      p += u0.x * vv[0];  p += u0.y * vv[1];  p += u0.z * vv[2];  p += u0.w * vv[3];
      p += u1.x * vv[4];  p += u1.y * vv[5];  p += u1.z * vv[6];  p += u1.w * vv[7];
      p += u2.x * vv[8];  p += u2.y * vv[9];  p += u2.z * vv[10]; p += u2.w * vv[11];
      p += u3.x * vv[12]; p += u3.y * vv[13]; p += u3.z * vv[14]; p += u3.w * vv[15];
      // reduce over the quad (lanes 4c..4c+3 hold capsule c's 64 o-elements)
      p += __shfl_xor(p, 1);
      p += __shfl_xor(p, 2);
      float bn = p;
      if (MODE == 2) bn += bpre[k];
      if (MODE == 1 && (l & 3) == 0)
        bij[((size_t)b * R_ + rbase + k) * C_ + (l >> 2)] = bn;
      // softmax over 16 capsules (each c replicated x4 across the wave)
      float mx = bn;
#pragma unroll
      for (int d = 1; d < 64; d <<= 1) mx = fmaxf(mx, __shfl_xor(mx, d));
      float ex = __expf(bn - mx);
      float tot = ex;
#pragma unroll
      for (int d = 1; d < 64; d <<= 1) tot += __shfl_xor(tot, d);
      cval = 4.0f * ex / tot;  // wave sum counts each capsule 4x
    }
    sacc[0]  += cval * u0.x; sacc[1]  += cval * u0.y; sacc[2]  += cval * u0.z; sacc[3]  += cval * u0.w;
    sacc[4]  += cval * u1.x; sacc[5]  += cval * u1.y; sacc[6]  += cval * u1.z; sacc[7]  += cval * u1.w;
    sacc[8]  += cval * u2.x; sacc[9]  += cval * u2.y; sacc[10] += cval * u2.z; sacc[11] += cval * u2.w;
    sacc[12] += cval * u3.x; sacc[13] += cval * u3.y; sacc[14] += cval * u3.z; sacc[15] += cval * u3.w;
  }

  // combine the 4 waves' partial s (s kept in NORMAL co-order; it's tiny/L2-hot)
  __shared__ float sp[4][16][64];
#pragma unroll
  for (int j = 0; j < 16; ++j) sp[w][j][l] = sacc[j];
  __syncthreads();
#pragma unroll
  for (int q = 0; q < 4; ++q) {
    const int co = threadIdx.x + q * 256;
    const int jj = co & 15, ll = co >> 4;
    // sacc index j corresponds to logical o-offset j within lane ll's 16 columns:
    // logical co = ll*16 + (j4*4+e) = ll*16 + j  -> same mapping as before.
    float val = sp[0][jj][ll] + sp[1][jj][ll] + sp[2][jj][ll] + sp[3][jj][ll];
    atomicAdd(&s[(size_t)b * CO_ + co], val);
  }
}

// ---------------- squash (elementwise, per reference) ----------------
__global__ __launch_bounds__(256) void squash_kernel(const float* __restrict__ s,
                                                     float* __restrict__ v) {
  const int i = blockIdx.x * 256 + threadIdx.x;
  const float t = s[i];
  const float sq = t * t;
  v[i] = sq / (1.0f + sq) * t * rsqrtf(sq + 1e-8f);
}

extern "C" void kernel_launch(void* const* d_in, const int* in_sizes, int n_in,
                              void* d_out, int out_size, void* d_ws, size_t ws_size,
                              hipStream_t stream) {
  (void)in_sizes; (void)n_in; (void)out_size; (void)ws_size;
  const float* x = (const float*)d_in[0];
  const float* W = (const float*)d_in[1];
  float* out = (float*)d_out;

  char* ws = (char*)d_ws;
  float* u = (float*)ws;                                   // 603,979,776 B (permuted layout)
  size_t off = (size_t)B_ * R_ * CO_ * sizeof(float);
  float* bij = (float*)(ws + off);                         // 9,437,184 B
  off += (size_t)B_ * R_ * C_ * sizeof(float);
  float* s = (float*)(ws + off);                           // 524,288 B
  off += (size_t)B_ * CO_ * sizeof(float);
  float* vbuf = (float*)(ws + off);                        // 524,288 B

  const size_t s_bytes = (size_t)B_ * CO_ * sizeof(float);

  uhat_kernel<<<2 * R_, 512, 0, stream>>>(x, W, u);

  // iteration 0: c = 1/16
  hipMemsetAsync(s, 0, s_bytes, stream);
  route_kernel<0><<<B_ * 36, 256, 0, stream>>>(u, nullptr, bij, s);
  squash_kernel<<<(B_ * CO_) / 256, 256, 0, stream>>>(s, vbuf);

  // iteration 1: b = a1
  hipMemsetAsync(s, 0, s_bytes, stream);
  route_kernel<1><<<B_ * 36, 256, 0, stream>>>(u, vbuf, bij, s);
  squash_kernel<<<(B_ * CO_) / 256, 256, 0, stream>>>(s, vbuf);

  // iteration 2: b = a1 + a2
  hipMemsetAsync(s, 0, s_bytes, stream);
  route_kernel<2><<<B_ * 36, 256, 0, stream>>>(u, vbuf, bij, s);
  squash_kernel<<<(B_ * CO_) / 256, 256, 0, stream>>>(s, out);
}